// Round 4
// baseline (29.350 us; speedup 1.0000x reference)
//
#include <hip/hip_runtime.h>

#define D_IN 64
#define D_OUT 64
#define NS 8        // NUM_SPLINES
#define NK 12       // knots per (o,d)
#define NREC 13     // interval records: idx = count(x >= t[j]) in [0,12]
#define KAN_EPS 1e-8f

// per-(o,d,interval) cubic coeffs of sum_s B3_s(x)*cp_s + 0.1*(w3*x - w1)
__device__ float4 g_rec[D_OUT * D_IN * NREC];   // 832 KB
__device__ float4 g_awf[D_OUT * D_IN];          // {w0, 2*w1, w2, 0}
__device__ int    g_mism[16];                   // knot o-uniformity flags (0 = shared)

// ---------- polynomial helpers ----------
struct P4 { float c0, c1, c2, c3; };
__device__ inline P4 p_scal(P4 p, float s) { return {p.c0*s, p.c1*s, p.c2*s, p.c3*s}; }
__device__ inline P4 p_add(P4 a, P4 b) { return {a.c0+b.c0, a.c1+b.c1, a.c2+b.c2, a.c3+b.c3}; }
__device__ inline P4 p_mul_xma(P4 p, float a) { return {-a*p.c0, p.c0 - a*p.c1, p.c1 - a*p.c2, p.c2 - a*p.c3}; }
__device__ inline P4 p_mul_bmx(P4 p, float b) { return {b*p.c0, b*p.c1 - p.c0, b*p.c2 - p.c1, b*p.c3 - p.c2}; }

// ---------- fused prep ----------
// blocks [0,208):   per-(o,d,iv13) piecewise-cubic records
// blocks [208,224): per-(o,d) act weights + knot o-uniformity check
// blocks [224,736): per-(bn,d) feature records P1/P2
__global__ __launch_bounds__(256)
void kan_prep_all(const float* __restrict__ cp,     // (64,64,8)
                  const float* __restrict__ knots,  // (64,64,12)
                  const float* __restrict__ aw,     // (64,64,4)
                  const float* __restrict__ x,      // (4,512,64)
                  float4* __restrict__ P1,          // ws: [64][2048] {x,x2,x3,cnt}
                  float4* __restrict__ P2)          // ws: [64][2048] {relu,Ra,Rb,0}
{
    const int blk = blockIdx.x;
    const int tid = threadIdx.x;

    if (blk < 208) {
        int flat = blk * 256 + tid;          // < 53248 exactly
        int iv13 = flat % NREC;
        int od   = flat / NREC;

        float t[NK];
        #pragma unroll
        for (int j = 0; j < NK; ++j) t[j] = knots[od * NK + j];
        auto tk = [&](int j) -> float {
            if (j < 0)  return t[0]  + (float)j;
            if (j > 11) return t[11] + (float)(j - 11);
            return t[j];
        };

        P4 sp = {0.f, 0.f, 0.f, 0.f};
        int iv = iv13 - 1;
        if (iv >= 0 && iv <= 10) {
            float tL0 = tk(iv),   tL1 = tk(iv-1), tL2 = tk(iv-2);
            float tR1 = tk(iv+1), tR2 = tk(iv+2), tR3 = tk(iv+3);
            float R1  = 1.f / (tR1 - tL0 + KAN_EPS);
            float R2a = 1.f / (tR1 - tL1 + KAN_EPS);
            float R2b = 1.f / (tR2 - tL0 + KAN_EPS);
            float R3a = 1.f / (tR1 - tL2 + KAN_EPS);
            float R3b = 1.f / (tR2 - tL1 + KAN_EPS);
            float R3c = 1.f / (tR3 - tL0 + KAN_EPS);

            P4 N0 = {1.f, 0.f, 0.f, 0.f}, N1, N2, N3, t0p, t1p, t2p, sv;
            t0p = p_scal(N0, R1);
            N0 = p_mul_bmx(t0p, tR1);
            N1 = p_mul_xma(t0p, tL0);
            t0p = p_scal(N0, R2a);
            N0 = p_mul_bmx(t0p, tR1);
            sv = p_mul_xma(t0p, tL1);
            t1p = p_scal(N1, R2b);
            N1 = p_add(sv, p_mul_bmx(t1p, tR2));
            N2 = p_mul_xma(t1p, tL0);
            t0p = p_scal(N0, R3a);
            N0 = p_mul_bmx(t0p, tR1);
            sv = p_mul_xma(t0p, tL2);
            t1p = p_scal(N1, R3b);
            N1 = p_add(sv, p_mul_bmx(t1p, tR2));
            sv = p_mul_xma(t1p, tL1);
            t2p = p_scal(N2, R3c);
            N2 = p_add(sv, p_mul_bmx(t2p, tR3));
            N3 = p_mul_xma(t2p, tL0);

            float cpv[4];
            #pragma unroll
            for (int r = 0; r < 4; ++r) {
                int i = iv - 3 + r;
                cpv[r] = (i >= 0 && i <= 7) ? cp[od * NS + i] : 0.f;
            }
            sp = p_add(p_add(p_scal(N0, cpv[0]), p_scal(N1, cpv[1])),
                       p_add(p_scal(N2, cpv[2]), p_scal(N3, cpv[3])));
        }
        float w1 = aw[od * 4 + 1];
        float w3 = aw[od * 4 + 3];
        sp.c0 -= 0.1f * w1;
        sp.c1 += 0.1f * w3;
        g_rec[flat] = make_float4(sp.c0, sp.c1, sp.c2, sp.c3);

    } else if (blk < 224) {
        int od = (blk - 208) * 256 + tid;    // < 4096 exactly
        float w0 = aw[od * 4 + 0];
        float w1 = aw[od * 4 + 1];
        float w2 = aw[od * 4 + 2];
        g_awf[od] = make_float4(w0, 2.0f * w1, w2, 0.0f);

        // knot row identical to o=0 row?
        int d = od & 63;
        int m = 0;
        #pragma unroll
        for (int j = 0; j < NK; ++j)
            m |= (knots[od * NK + j] != knots[d * NK + j]) ? 1 : 0;
        __shared__ int sm;
        if (tid == 0) sm = 0;
        __syncthreads();
        if (m) atomicOr(&sm, 1);
        __syncthreads();
        if (tid == 0) g_mism[blk - 208] = sm;

    } else {
        // per-(bn,d) features; idx bn-major -> coalesced x read
        int idx = (blk - 224) * 256 + tid;   // < 131072 exactly
        int bn = idx >> 6, d = idx & 63;
        float xv = x[idx];                   // x[bn*64+d]
        int cnt = 0;
        #pragma unroll
        for (int j = 0; j < NK; ++j) cnt += (xv >= knots[d * NK + j]) ? 1 : 0;
        float v  = __expf(-xv);
        float Ra = __builtin_amdgcn_rcpf(1.f + v * v);   // sigma(2x) -> tanh = 2Ra-1
        float Rb = __builtin_amdgcn_rcpf(1.f + v);       // sigma(x)
        P1[(d << 11) + bn] = make_float4(xv, xv * xv, xv * xv * xv, (float)cnt);
        P2[(d << 11) + bn] = make_float4(fmaxf(xv, 0.f), Ra, Rb, 0.f);
    }
}

// ---------- main kernel ----------
// grid (64, 8); block 512 = 32 bn-lanes x 8 o x 2 d-halves
__global__ __launch_bounds__(512)
void kan_main(const float4* __restrict__ P1,
              const float4* __restrict__ P2,
              const float* __restrict__ knots,
              float* __restrict__ out)          // (4,64,512)
{
    __shared__ float s_red[256];

    const int tid = threadIdx.x;
    const int bnl = tid & 31;
    const int og  = (tid >> 5) & 7;
    const int dh  = tid >> 8;
    const int bn  = blockIdx.x * 32 + bnl;
    const int o   = blockIdx.y * 8 + og;
    const int dbase = dh << 5;

    int mm = 0;
    #pragma unroll
    for (int k = 0; k < 16; ++k) mm |= g_mism[k];

    float a0 = 0.f, a1 = 0.f, w0acc = 0.f, w1acc = 0.f;

    if (mm == 0) {
        // knots shared across o: cnt from P1.w
        #pragma unroll 4
        for (int i = 0; i < 32; ++i) {
            const int d  = dbase + i;
            const int od = (o << 6) + d;
            const float4 p1 = P1[(d << 11) + bn];
            const float4 p2 = P2[(d << 11) + bn];
            const float4 cf = g_rec[od * NREC + (int)p1.w];
            float t = fmaf(cf.y, p1.x, cf.x);
            t = fmaf(cf.z, p1.y, t);
            t = fmaf(cf.w, p1.z, t);
            const float4 w = g_awf[od];
            float s = p2.x * w.x;
            s = fmaf(p2.y, w.y, s);
            s = fmaf(p2.z, w.z, s);
            if (i & 1) { a1 += t; w1acc += s; }
            else       { a0 += t; w0acc += s; }
        }
    } else {
        // general path: per-(o,d) interval search
        #pragma unroll 2
        for (int i = 0; i < 32; ++i) {
            const int d  = dbase + i;
            const int od = (o << 6) + d;
            const float4 p1 = P1[(d << 11) + bn];
            const float4 p2 = P2[(d << 11) + bn];
            const float xv = p1.x;
            int cnt = 0;
            #pragma unroll
            for (int j = 0; j < NK; ++j) cnt += (xv >= knots[od * NK + j]) ? 1 : 0;
            const float4 cf = g_rec[od * NREC + cnt];
            float t = fmaf(cf.y, p1.x, cf.x);
            t = fmaf(cf.z, p1.y, t);
            t = fmaf(cf.w, p1.z, t);
            const float4 w = g_awf[od];
            float s = p2.x * w.x;
            s = fmaf(p2.y, w.y, s);
            s = fmaf(p2.z, w.z, s);
            if (i & 1) { a1 += t; w1acc += s; }
            else       { a0 += t; w0acc += s; }
        }
    }

    float tot = (a0 + a1) + 0.1f * (w0acc + w1acc);

    if (dh) s_red[tid & 255] = tot;
    __syncthreads();
    if (!dh) {
        tot += s_red[tid];
        const int b = bn >> 9;
        const int n = bn & 511;
        out[(((b << 6) + o) << 9) | n] = tot;
    }
}

extern "C" void kernel_launch(void* const* d_in, const int* in_sizes, int n_in,
                              void* d_out, int out_size, void* d_ws, size_t ws_size,
                              hipStream_t stream) {
    const float* x     = (const float*)d_in[0];  // (4,512,64)
    const float* cp    = (const float*)d_in[1];  // (64,64,8)
    const float* knots = (const float*)d_in[2];  // (64,64,12)
    const float* aw    = (const float*)d_in[3];  // (64,64,4)
    float* out = (float*)d_out;                  // (4,64,512)

    float4* P1 = (float4*)d_ws;                  // 2 MB
    float4* P2 = P1 + D_IN * 2048;               // 2 MB

    kan_prep_all<<<736, 256, 0, stream>>>(cp, knots, aw, x, P1, P2);

    dim3 grid(2048 / 32, D_OUT / 8);             // (64, 8)
    kan_main<<<grid, 512, 0, stream>>>(P1, P2, knots, out);
}

// Round 5
// 24.551 us; speedup vs baseline: 1.1955x; 1.1955x over previous
//
#include <hip/hip_runtime.h>

#define D_IN 64
#define D_OUT 64
#define NS 8
#define NK 12
#define NF 12                     // features per d: 8 basis + relu,tanh,sig,x
#define KTOT (D_IN * NF)          // 768
#define KAN_EPS 1e-8f
#define NBN 2048
#define KSPLIT 8
#define KCH (KTOT / KSPLIT)       // 96 k per split = 8 d

__device__ int g_mism[16];        // knot o-uniformity flags (0 = shared across o)

// ws layout (floats):
//   F       [768][2048]      @ 0          (6.29 MB)
//   Wt      [768][64]        @ F_ELEMS    (196 KB)
//   partial [8][64][2048]    @ F_ELEMS+WT (4 MB)
#define F_ELEMS  (KTOT * NBN)
#define WT_ELEMS (KTOT * D_OUT)

// exact replication of the reference Cox-de Boor recursion (fp32)
__device__ inline void basis8(float xv, const float* __restrict__ t, float* __restrict__ B)
{
    float Bb[11];
    #pragma unroll
    for (int i = 0; i < 11; ++i) Bb[i] = (xv >= t[i] && xv < t[i + 1]) ? 1.f : 0.f;
    #pragma unroll
    for (int i = 0; i < 10; ++i)
        Bb[i] = (xv - t[i]) * (1.f / (t[i + 1] - t[i] + KAN_EPS)) * Bb[i]
              + (t[i + 2] - xv) * (1.f / (t[i + 2] - t[i + 1] + KAN_EPS)) * Bb[i + 1];
    #pragma unroll
    for (int i = 0; i < 9; ++i)
        Bb[i] = (xv - t[i]) * (1.f / (t[i + 2] - t[i] + KAN_EPS)) * Bb[i]
              + (t[i + 3] - xv) * (1.f / (t[i + 3] - t[i + 1] + KAN_EPS)) * Bb[i + 1];
    #pragma unroll
    for (int i = 0; i < 8; ++i)
        Bb[i] = (xv - t[i]) * (1.f / (t[i + 3] - t[i] + KAN_EPS)) * Bb[i]
              + (t[i + 4] - xv) * (1.f / (t[i + 4] - t[i + 1] + KAN_EPS)) * Bb[i + 1];
    #pragma unroll
    for (int i = 0; i < 8; ++i) B[i] = Bb[i];
}

// ---------- prep: features F + weights Wt + uniformity flags ----------
// blocks [0,512):   per (d,bn) feature rows (d uniform within block -> knot s_loads)
// blocks [512,528): Wt build + knot o-uniformity check
__global__ __launch_bounds__(256)
void kan_prep(const float* __restrict__ cp,     // (64,64,8)
              const float* __restrict__ knots,  // (64,64,12)
              const float* __restrict__ aw,     // (64,64,4)
              const float* __restrict__ x,      // (4,512,64)
              float* __restrict__ F,
              float* __restrict__ Wt)
{
    const int blk = blockIdx.x;
    const int tid = threadIdx.x;

    if (blk < 512) {
        const int idx = blk * 256 + tid;        // 131072, d-major
        const int d  = idx >> 11;               // uniform within block
        const int bn = idx & 2047;
        const float xv = x[bn * D_IN + d];

        float t[NK];
        #pragma unroll
        for (int j = 0; j < NK; ++j) t[j] = knots[d * NK + j];   // o=0 row

        float B[8];
        basis8(xv, t, B);

        float* __restrict__ Fr = F + d * NF * NBN + bn;
        #pragma unroll
        for (int s = 0; s < 8; ++s) Fr[s * NBN] = B[s];

        const float v  = __expf(-xv);
        const float Ra = __builtin_amdgcn_rcpf(1.f + v * v);
        const float Rb = __builtin_amdgcn_rcpf(1.f + v);
        Fr[8  * NBN] = fmaxf(xv, 0.f);          // relu
        Fr[9  * NBN] = 2.f * Ra - 1.f;          // tanh
        Fr[10 * NBN] = Rb;                      // sigmoid
        Fr[11 * NBN] = xv;                      // identity

    } else {
        const int od = (blk - 512) * 256 + tid; // 4096: o*64+d
        const int o = od >> 6, d = od & 63;
        #pragma unroll
        for (int s = 0; s < 8; ++s) Wt[(d * NF + s) * D_OUT + o] = cp[od * NS + s];
        #pragma unroll
        for (int a = 0; a < 4; ++a) Wt[(d * NF + 8 + a) * D_OUT + o] = 0.1f * aw[od * 4 + a];

        int m = 0;
        #pragma unroll
        for (int j = 0; j < NK; ++j)
            m |= (knots[od * NK + j] != knots[d * NK + j]) ? 1 : 0;
        __shared__ int sm;
        if (tid == 0) sm = 0;
        __syncthreads();
        if (m) atomicOr(&sm, 1);
        __syncthreads();
        if (tid == 0) g_mism[blk - 512] = sm;
    }
}

// ---------- GEMM: partial[ks][o][bn] = sum_{k in split} Wt[k][o] * F[k][bn] ----------
// grid (32 bn-tiles, 8 ksplit); block 512 = 64 bn-lanes x 8 o-groups
__global__ __launch_bounds__(512)
void kan_gemm(const float* __restrict__ F,
              const float* __restrict__ Wt,
              const float* __restrict__ knots,
              const float* __restrict__ cp,
              const float* __restrict__ aw,
              const float* __restrict__ x,
              float* __restrict__ partial)
{
    const int lane = threadIdx.x & 63;
    const int og   = __builtin_amdgcn_readfirstlane(threadIdx.x >> 6);  // 0..7, wave-uniform
    const int bn   = blockIdx.x * 64 + lane;
    const int ks   = blockIdx.y;                                        // 0..7

    float acc[8] = {0.f, 0.f, 0.f, 0.f, 0.f, 0.f, 0.f, 0.f};

    int mm = 0;
    #pragma unroll
    for (int k = 0; k < 16; ++k) mm |= g_mism[k];

    if (mm == 0) {
        const float* __restrict__ Fp = F  + (size_t)(ks * KCH) * NBN + bn;
        const float* __restrict__ Wp = Wt + (ks * KCH) * D_OUT + og * 8;  // wave-uniform -> s_load
        #pragma unroll 8
        for (int k = 0; k < KCH; ++k) {
            const float f = Fp[(size_t)k * NBN];
            #pragma unroll
            for (int j = 0; j < 8; ++j)
                acc[j] = fmaf(f, Wp[k * D_OUT + j], acc[j]);
        }
    } else {
        // general fallback: knots differ across o -> recompute basis per (o,d)
        for (int d = ks * (KCH / NF); d < ks * (KCH / NF) + (KCH / NF); ++d) {
            const float xv = x[bn * D_IN + d];
            const float v  = __expf(-xv);
            const float Ra = __builtin_amdgcn_rcpf(1.f + v * v);
            const float Rb = __builtin_amdgcn_rcpf(1.f + v);
            const float fr = fmaxf(xv, 0.f), fth = 2.f * Ra - 1.f;
            #pragma unroll
            for (int j = 0; j < 8; ++j) {
                const int o  = og * 8 + j;
                const int od = o * D_IN + d;
                float t[NK];
                #pragma unroll
                for (int jj = 0; jj < NK; ++jj) t[jj] = knots[od * NK + jj];
                float B[8];
                basis8(xv, t, B);
                float sp = 0.f;
                #pragma unroll
                for (int s = 0; s < NS; ++s) sp += B[s] * cp[od * NS + s];
                sp += 0.1f * (aw[od * 4 + 0] * fr + aw[od * 4 + 1] * fth
                            + aw[od * 4 + 2] * Rb + aw[od * 4 + 3] * xv);
                acc[j] += sp;
            }
        }
    }

    float* __restrict__ pp = partial + ((size_t)ks * D_OUT + og * 8) * NBN + bn;
    #pragma unroll
    for (int j = 0; j < 8; ++j) pp[(size_t)j * NBN] = acc[j];
}

// ---------- reduce: out[b,o,n] = sum_ks partial[ks][o][bn] ----------
// grid 128 blocks x 256 thr; each thread does 4 consecutive bn via float4
__global__ __launch_bounds__(256)
void kan_reduce(const float4* __restrict__ partial, float* __restrict__ out)
{
    const int q = blockIdx.x * 256 + threadIdx.x;    // 32768 float4 slots
    float4 s = partial[q];
    #pragma unroll
    for (int ks = 1; ks < KSPLIT; ++ks) {
        const float4 p = partial[(size_t)ks * (D_OUT * NBN / 4) + q];
        s.x += p.x; s.y += p.y; s.z += p.z; s.w += p.w;
    }
    const int idx = q * 4;                 // = o*2048 + bn
    const int o  = idx >> 11;
    const int bn = idx & 2047;
    const int b  = bn >> 9;
    const int n  = bn & 511;
    *(float4*)&out[(((b << 6) + o) << 9) + n] = s;   // 512|2048 % 4 == 0: no straddle
}

extern "C" void kernel_launch(void* const* d_in, const int* in_sizes, int n_in,
                              void* d_out, int out_size, void* d_ws, size_t ws_size,
                              hipStream_t stream) {
    const float* x     = (const float*)d_in[0];  // (4,512,64)
    const float* cp    = (const float*)d_in[1];  // (64,64,8)
    const float* knots = (const float*)d_in[2];  // (64,64,12)
    const float* aw    = (const float*)d_in[3];  // (64,64,4)
    float* out = (float*)d_out;                  // (4,64,512)

    float* F       = (float*)d_ws;
    float* Wt      = F + F_ELEMS;
    float* partial = Wt + WT_ELEMS;

    kan_prep<<<528, 256, 0, stream>>>(cp, knots, aw, x, F, Wt);

    dim3 ggrid(NBN / 64, KSPLIT);               // (32, 8)
    kan_gemm<<<ggrid, 512, 0, stream>>>(F, Wt, knots, cp, aw, x, partial);

    kan_reduce<<<128, 256, 0, stream>>>((const float4*)partial, out);
}